// Round 6
// baseline (1487.230 us; speedup 1.0000x reference)
//
#include <hip/hip_runtime.h>
#include <hip/hip_bf16.h>

#define D 128
#define GRP 64            // nodes per group
#define CAPB_MAX 2048     // LDS staging size (>= runtime CAPB)

__device__ __forceinline__ float bf2f(unsigned short u) {
    union { unsigned int i; float f; } c;
    c.i = ((unsigned int)u) << 16;
    return c.f;
}
__device__ __forceinline__ float bits2f(unsigned int i) {
    union { unsigned int i; float f; } c;
    c.i = i;
    return c.f;
}
__device__ __forceinline__ unsigned short f2bf(float f) {
    __hip_bfloat16 h = __float2bfloat16(f);
    return *(unsigned short*)&h;
}

// Probe dtypes at runtime (one wave). flags[0]=1 if x is fp32; flags[1]=1 if ei is int64.
__global__ __launch_bounds__(64) void probe_kernel(
    const unsigned short* __restrict__ x,
    const long long* __restrict__ ei64,
    int nNodes, int* __restrict__ flags)
{
    const int lane = threadIdx.x;
    int cnt = 0;
    for (int i = lane; i < 512; i += 64) {
        float v = bf2f(x[i]);
        if (!(fabsf(v) < 1e4f)) cnt++;   // NaN counts
    }
    unsigned long long m1 = __ballot(cnt > 0);
    long long v = ei64[lane];
    int bad = (v < 0 || v >= (long long)nNodes) ? 1 : 0;
    unsigned long long m2 = __ballot(bad);
    if (lane == 0) {
        flags[0] = (__popcll(m1) > 2) ? 1 : 0;
        flags[1] = (m2 == 0) ? 1 : 0;
    }
}

// ---------- GEMM: out = in @ W (+ b). Register-blocked 64-row tiles. ----------
// in_f32 / out_f32: 1 = fp32, 0 = bf16, -1 = follow flags[0].
__global__ __launch_bounds__(256) void gemm_kernel(
    const void* __restrict__ inv, const void* __restrict__ Wv,
    const void* __restrict__ bv, void* __restrict__ outv,
    int nNodes, const int* __restrict__ flags,
    int in_f32p, int out_f32p, int add_bias)
{
    __shared__ float Ws[D * D];   // 64 KB
    __shared__ float bs[D];

    const int xf32 = flags[0];
    const int in_f32  = (in_f32p  < 0) ? xf32 : in_f32p;
    const int out_f32 = (out_f32p < 0) ? xf32 : out_f32p;

    if (xf32) {
        const float* W = (const float*)Wv;
        for (int i = threadIdx.x; i < D * D; i += 256) Ws[i] = W[i];
        if (threadIdx.x < D)
            bs[threadIdx.x] = add_bias ? ((const float*)bv)[threadIdx.x] : 0.f;
    } else {
        const unsigned short* W = (const unsigned short*)Wv;
        for (int i = threadIdx.x; i < D * D; i += 256) Ws[i] = bf2f(W[i]);
        if (threadIdx.x < D)
            bs[threadIdx.x] = add_bias ? bf2f(((const unsigned short*)bv)[threadIdx.x]) : 0.f;
    }
    __syncthreads();

    const int cg = threadIdx.x & 31;
    const int rg = threadIdx.x >> 5;
    const int c = cg * 4;
    const int row0 = blockIdx.x * 64 + rg * 8;

    size_t rIdx[8];
    #pragma unroll
    for (int r = 0; r < 8; ++r) {
        int row = row0 + r;
        rIdx[r] = (size_t)(row < nNodes ? row : nNodes - 1);
    }

    float4 acc[8];
    #pragma unroll
    for (int r = 0; r < 8; ++r)
        acc[r] = make_float4(bs[c], bs[c + 1], bs[c + 2], bs[c + 3]);

    if (in_f32) {
        const float* in = (const float*)inv;
        for (int k = 0; k < D; k += 4) {
            float4 w0 = *(const float4*)&Ws[(k + 0) * D + c];
            float4 w1 = *(const float4*)&Ws[(k + 1) * D + c];
            float4 w2 = *(const float4*)&Ws[(k + 2) * D + c];
            float4 w3 = *(const float4*)&Ws[(k + 3) * D + c];
            #pragma unroll
            for (int r = 0; r < 8; ++r) {
                float4 a = *(const float4*)(in + rIdx[r] * D + k);
                acc[r].x += a.x * w0.x + a.y * w1.x + a.z * w2.x + a.w * w3.x;
                acc[r].y += a.x * w0.y + a.y * w1.y + a.z * w2.y + a.w * w3.y;
                acc[r].z += a.x * w0.z + a.y * w1.z + a.z * w2.z + a.w * w3.z;
                acc[r].w += a.x * w0.w + a.y * w1.w + a.z * w2.w + a.w * w3.w;
            }
        }
    } else {
        const unsigned short* in = (const unsigned short*)inv;
        for (int k = 0; k < D; k += 4) {
            float4 w0 = *(const float4*)&Ws[(k + 0) * D + c];
            float4 w1 = *(const float4*)&Ws[(k + 1) * D + c];
            float4 w2 = *(const float4*)&Ws[(k + 2) * D + c];
            float4 w3 = *(const float4*)&Ws[(k + 3) * D + c];
            #pragma unroll
            for (int r = 0; r < 8; ++r) {
                ushort4 u = *(const ushort4*)(in + rIdx[r] * D + k);
                float ax = bf2f(u.x), ay = bf2f(u.y), az = bf2f(u.z), aw = bf2f(u.w);
                acc[r].x += ax * w0.x + ay * w1.x + az * w2.x + aw * w3.x;
                acc[r].y += ax * w0.y + ay * w1.y + az * w2.y + aw * w3.y;
                acc[r].z += ax * w0.z + ay * w1.z + az * w2.z + aw * w3.z;
                acc[r].w += ax * w0.w + ay * w1.w + az * w2.w + aw * w3.w;
            }
        }
    }

    #pragma unroll
    for (int r = 0; r < 8; ++r) {
        int row = row0 + r;
        if (row >= nNodes) break;
        if (out_f32) {
            ((float4*)outv)[(size_t)row * 32 + cg] = acc[r];
        } else {
            ushort4 o;
            o.x = f2bf(acc[r].x); o.y = f2bf(acc[r].y);
            o.z = f2bf(acc[r].z); o.w = f2bf(acc[r].w);
            ((ushort4*)outv)[(size_t)row * 32 + cg] = o;
        }
    }
}

// ---------- build: append packed edge (s | r<<20) to its 64-node GROUP run ----------
// Hot padded counters (1563 lines) + dense append regions (16 edges/line)
// replace 100k scattered counters/regions -> line reuse, low write churn.
__global__ __launch_bounds__(256) void build_grp(
    const void* __restrict__ eiv, int* __restrict__ gcnt, unsigned int* __restrict__ grp,
    int* __restrict__ ovfCnt, int* __restrict__ ovfHead, int2* __restrict__ ovf,
    int nEdges, int CAPB, const int* __restrict__ flags)
{
    int e = blockIdx.x * 256 + threadIdx.x;
    if (e >= nEdges) return;
    int s, d;
    if (flags[1]) {
        const long long* ei = (const long long*)eiv;
        s = (int)ei[e];
        d = (int)ei[(size_t)nEdges + e];
    } else {
        const int* ei = (const int*)eiv;
        s = ei[e];
        d = ei[(size_t)nEdges + e];
    }
    const int b = d >> 6;                 // group id
    const unsigned int p = (unsigned int)s | ((unsigned int)(d & 63) << 20);
    int pos = atomicAdd(&gcnt[(size_t)b * 16], 1);   // padded: 1 counter / 64B line
    if (pos < CAPB) {
        __builtin_nontemporal_store(p, &grp[(size_t)b * CAPB + pos]);
    } else {
        int idx = atomicAdd(ovfCnt, 1);   // < nEdges guaranteed
        int old = atomicExch(&ovfHead[b], idx);
        ovf[idx] = make_int2(old, (int)p);
    }
}

// ---------- accumulate: one block per 64-node group, LDS f32 accumulator ----------
// Edge list contiguous per group -> coalesced staging; y-row loads fully
// independent (4-deep batches/wave); ds_add_f32 accumulation; coalesced epilogue.
__global__ __launch_bounds__(256, 4) void accum_grp(
    const unsigned int* __restrict__ yu,   // y as bf16 pairs (N x 64 uints)
    const int* __restrict__ gcnt, const unsigned int* __restrict__ grp,
    const int* __restrict__ ovfHead, const int2* __restrict__ ovf,
    const void* __restrict__ bv, void* __restrict__ outv,
    int nNodes, int CAPB, const int* __restrict__ flags)
{
    __shared__ float acc[GRP][D];          // 32 KB
    __shared__ unsigned int stage[CAPB_MAX];  // 8 KB

    const int b = blockIdx.x;
    const int n0 = b << 6;
    const int tid = threadIdx.x;
    const int w = tid >> 6, lane = tid & 63;
    const int xf32 = flags[0];

    for (int i = tid; i < GRP * D; i += 256) ((float*)acc)[i] = 0.f;

    const int cnt = gcnt[(size_t)b * 16];
    const int m = cnt < CAPB ? cnt : CAPB;
    for (int i = tid; i < m; i += 256) stage[i] = grp[(size_t)b * CAPB + i];
    __syncthreads();

    int i = w;
    for (; i + 12 < m; i += 16) {   // 4 edges per wave in flight
        unsigned int p0 = stage[i], p1 = stage[i + 4], p2 = stage[i + 8], p3 = stage[i + 12];
        unsigned int u0 = yu[(size_t)(p0 & 0xFFFFF) * 64 + lane];
        unsigned int u1 = yu[(size_t)(p1 & 0xFFFFF) * 64 + lane];
        unsigned int u2 = yu[(size_t)(p2 & 0xFFFFF) * 64 + lane];
        unsigned int u3 = yu[(size_t)(p3 & 0xFFFFF) * 64 + lane];
        atomicAdd(&acc[p0 >> 20][2 * lane],     bits2f(u0 << 16));
        atomicAdd(&acc[p0 >> 20][2 * lane + 1], bits2f(u0 & 0xFFFF0000u));
        atomicAdd(&acc[p1 >> 20][2 * lane],     bits2f(u1 << 16));
        atomicAdd(&acc[p1 >> 20][2 * lane + 1], bits2f(u1 & 0xFFFF0000u));
        atomicAdd(&acc[p2 >> 20][2 * lane],     bits2f(u2 << 16));
        atomicAdd(&acc[p2 >> 20][2 * lane + 1], bits2f(u2 & 0xFFFF0000u));
        atomicAdd(&acc[p3 >> 20][2 * lane],     bits2f(u3 << 16));
        atomicAdd(&acc[p3 >> 20][2 * lane + 1], bits2f(u3 & 0xFFFF0000u));
    }
    for (; i < m; i += 4) {
        unsigned int p0 = stage[i];
        unsigned int u0 = yu[(size_t)(p0 & 0xFFFFF) * 64 + lane];
        atomicAdd(&acc[p0 >> 20][2 * lane],     bits2f(u0 << 16));
        atomicAdd(&acc[p0 >> 20][2 * lane + 1], bits2f(u0 & 0xFFFF0000u));
    }

    if (w == 0 && cnt > CAPB) {   // rare overflow chain
        int cur = __builtin_amdgcn_readfirstlane(ovfHead[b]);
        while (cur >= 0) {
            int2 t = ovf[cur];
            unsigned int p = (unsigned int)__builtin_amdgcn_readfirstlane(t.y);
            unsigned int u = yu[(size_t)(p & 0xFFFFF) * 64 + lane];
            atomicAdd(&acc[p >> 20][2 * lane],     bits2f(u << 16));
            atomicAdd(&acc[p >> 20][2 * lane + 1], bits2f(u & 0xFFFF0000u));
            cur = __builtin_amdgcn_readfirstlane(t.x);
        }
    }
    __syncthreads();

    // epilogue: wave w writes rows w, w+4, ... ; lane covers dim pair (2l, 2l+1)
    for (int r = w; r < GRP; r += 4) {
        int node = n0 + r;
        if (node >= nNodes) break;
        float f0 = acc[r][2 * lane];
        float f1 = acc[r][2 * lane + 1];
        if (xf32) {
            float2 bb = ((const float2*)bv)[lane];
            float2 o; o.x = f0 + bb.x; o.y = f1 + bb.y;
            ((float2*)outv)[(size_t)node * 64 + lane] = o;
        } else {
            unsigned int ub = ((const unsigned int*)bv)[lane];
            f0 += bits2f(ub << 16);
            f1 += bits2f(ub & 0xFFFF0000u);
            unsigned int o = ((unsigned int)f2bf(f0)) | (((unsigned int)f2bf(f1)) << 16);
            ((unsigned int*)outv)[(size_t)node * 64 + lane] = o;
        }
    }
}

// ---------- fallback scatter (atomics) if ws too small / N too large ----------
__global__ __launch_bounds__(256) void scatter_kernel(
    const void* __restrict__ xv, const void* __restrict__ eiv,
    float* __restrict__ agg, int nEdges, const int* __restrict__ flags)
{
    long long tid = (long long)blockIdx.x * 256 + threadIdx.x;
    int e = (int)(tid >> 5);
    if (e >= nEdges) return;
    int q = (int)tid & 31;

    const int xf32 = flags[0];
    int s, d;
    if (flags[1]) {
        const long long* ei = (const long long*)eiv;
        s = (int)ei[e]; d = (int)ei[(size_t)nEdges + e];
    } else {
        const int* ei = (const int*)eiv;
        s = ei[e]; d = ei[(size_t)nEdges + e];
    }
    float4 v;
    if (xf32) {
        v = ((const float4*)xv)[(size_t)s * 32 + q];
    } else {
        ushort4 u = ((const ushort4*)xv)[(size_t)s * 32 + q];
        v.x = bf2f(u.x); v.y = bf2f(u.y); v.z = bf2f(u.z); v.w = bf2f(u.w);
    }
    float* ap = agg + (size_t)d * D + q * 4;
    atomicAdd(ap + 0, v.x);
    atomicAdd(ap + 1, v.y);
    atomicAdd(ap + 2, v.z);
    atomicAdd(ap + 3, v.w);
}

static inline size_t alignup(size_t v, size_t a) { return (v + a - 1) & ~(a - 1); }

extern "C" void kernel_launch(void* const* d_in, const int* in_sizes, int n_in,
                              void* d_out, int out_size, void* d_ws, size_t ws_size,
                              hipStream_t stream) {
    const void* x  = d_in[0];
    const void* ei = d_in[1];
    const void* W  = d_in[2];
    const void* b  = d_in[3];

    const int nNodes = in_sizes[0] / D;
    const int nEdges = in_sizes[1] / 2;
    const int NB = (nNodes + GRP - 1) / GRP;

    int* flags = (int*)d_ws;
    probe_kernel<<<1, 64, 0, stream>>>((const unsigned short*)x, (const long long*)ei,
                                       nNodes, flags);

    // fast path ws layout:
    // flags(512) | gcnt[NB*16] | ovfCnt(256B) | ovfHead[NB] | ovf[E] int2 | grp[NB*CAPB] | y[N*D] bf16
    int CAPB = 0;
    size_t off_gcnt = 512, off_ovfc = 0, off_head = 0, off_ovf = 0, off_grp = 0, off_y = 0;
    if (nNodes < (1 << 20)) {   // s must fit 20 bits in packed entry
        const int caps[2] = {2048, 1024};
        for (int ci = 0; ci < 2; ++ci) {
            int cap = caps[ci];
            size_t ogcnt = 512;
            size_t oovfc = alignup(ogcnt + 64ull * NB, 256);
            size_t ohead = oovfc + 256;
            size_t oovf  = alignup(ohead + 4ull * NB, 256);
            size_t ogrp  = alignup(oovf + 8ull * nEdges, 256);
            size_t oy    = alignup(ogrp + 4ull * cap * NB, 512);
            size_t need  = oy + (size_t)nNodes * D * 2;   // y bf16
            if (ws_size >= need) {
                CAPB = cap; off_gcnt = ogcnt; off_ovfc = oovfc; off_head = ohead;
                off_ovf = oovf; off_grp = ogrp; off_y = oy;
                break;
            }
        }
    }

    const int eblocks = (nEdges + 255) / 256;
    const int mblocks = (nNodes + 63) / 64;

    if (CAPB > 0) {
        int*          gcnt    = (int*)((char*)d_ws + off_gcnt);
        int*          ovfCnt  = (int*)((char*)d_ws + off_ovfc);
        int*          ovfHead = (int*)((char*)d_ws + off_head);
        int2*         ovf     = (int2*)((char*)d_ws + off_ovf);
        unsigned int* grp     = (unsigned int*)((char*)d_ws + off_grp);
        void*         y       = (void*)((char*)d_ws + off_y);

        // y = x @ W   (no bias; y stored bf16)
        gemm_kernel<<<mblocks, 256, 0, stream>>>(x, W, b, y, nNodes, flags,
                                                 /*in_f32*/-1, /*out_f32*/0, /*bias*/0);

        hipMemsetAsync(gcnt, 0, (off_head - off_gcnt), stream);      // gcnt = 0, ovfCnt = 0
        hipMemsetAsync(ovfHead, 0xFF, 4ull * NB, stream);            // heads = -1
        build_grp<<<eblocks, 256, 0, stream>>>(ei, gcnt, grp, ovfCnt, ovfHead, ovf,
                                               nEdges, CAPB, flags);

        accum_grp<<<NB, 256, 0, stream>>>((const unsigned int*)y, gcnt, grp,
                                          ovfHead, ovf, b, d_out,
                                          nNodes, CAPB, flags);
    } else {
        // fallback: atomic scatter into fp32 agg, then out = agg @ W + b
        float* agg = (float*)((char*)d_ws + 512);
        hipMemsetAsync(agg, 0, (size_t)nNodes * D * sizeof(float), stream);
        long long total = (long long)nEdges * 32;
        int sblocks = (int)((total + 255) / 256);
        scatter_kernel<<<sblocks, 256, 0, stream>>>(x, ei, agg, nEdges, flags);
        gemm_kernel<<<mblocks, 256, 0, stream>>>(agg, W, b, d_out, nNodes, flags,
                                                 /*in_f32*/1, /*out_f32*/-1, /*bias*/1);
    }
}

// Round 7
// 295.168 us; speedup vs baseline: 5.0386x; 5.0386x over previous
//
#include <hip/hip_runtime.h>
#include <hip/hip_bf16.h>

#define D 128
#define GRP 64            // nodes per group
#define NBMAX 4096        // max groups supported by fast path (N <= 256K)
#define CAPB_MAX 2048     // per-group capacity (mean 1024 at E/N=16; +32 sigma)

__device__ __forceinline__ float bf2f(unsigned short u) {
    union { unsigned int i; float f; } c;
    c.i = ((unsigned int)u) << 16;
    return c.f;
}
__device__ __forceinline__ float bits2f(unsigned int i) {
    union { unsigned int i; float f; } c;
    c.i = i;
    return c.f;
}
__device__ __forceinline__ unsigned short f2bf(float f) {
    __hip_bfloat16 h = __float2bfloat16(f);
    return *(unsigned short*)&h;
}

// Probe dtypes at runtime (one wave). flags[0]=1 if x is fp32; flags[1]=1 if ei is int64.
__global__ __launch_bounds__(64) void probe_kernel(
    const unsigned short* __restrict__ x,
    const long long* __restrict__ ei64,
    int nNodes, int* __restrict__ flags)
{
    const int lane = threadIdx.x;
    int cnt = 0;
    for (int i = lane; i < 512; i += 64) {
        float v = bf2f(x[i]);
        if (!(fabsf(v) < 1e4f)) cnt++;   // NaN counts
    }
    unsigned long long m1 = __ballot(cnt > 0);
    long long v = ei64[lane];
    int bad = (v < 0 || v >= (long long)nNodes) ? 1 : 0;
    unsigned long long m2 = __ballot(bad);
    if (lane == 0) {
        flags[0] = (__popcll(m1) > 2) ? 1 : 0;
        flags[1] = (m2 == 0) ? 1 : 0;
    }
}

// ---------- GEMM: out = in @ W (+ b). Register-blocked 64-row tiles. ----------
__global__ __launch_bounds__(256) void gemm_kernel(
    const void* __restrict__ inv, const void* __restrict__ Wv,
    const void* __restrict__ bv, void* __restrict__ outv,
    int nNodes, const int* __restrict__ flags,
    int in_f32p, int out_f32p, int add_bias)
{
    __shared__ float Ws[D * D];   // 64 KB
    __shared__ float bs[D];

    const int xf32 = flags[0];
    const int in_f32  = (in_f32p  < 0) ? xf32 : in_f32p;
    const int out_f32 = (out_f32p < 0) ? xf32 : out_f32p;

    if (xf32) {
        const float* W = (const float*)Wv;
        for (int i = threadIdx.x; i < D * D; i += 256) Ws[i] = W[i];
        if (threadIdx.x < D)
            bs[threadIdx.x] = add_bias ? ((const float*)bv)[threadIdx.x] : 0.f;
    } else {
        const unsigned short* W = (const unsigned short*)Wv;
        for (int i = threadIdx.x; i < D * D; i += 256) Ws[i] = bf2f(W[i]);
        if (threadIdx.x < D)
            bs[threadIdx.x] = add_bias ? bf2f(((const unsigned short*)bv)[threadIdx.x]) : 0.f;
    }
    __syncthreads();

    const int cg = threadIdx.x & 31;
    const int rg = threadIdx.x >> 5;
    const int c = cg * 4;
    const int row0 = blockIdx.x * 64 + rg * 8;

    size_t rIdx[8];
    #pragma unroll
    for (int r = 0; r < 8; ++r) {
        int row = row0 + r;
        rIdx[r] = (size_t)(row < nNodes ? row : nNodes - 1);
    }

    float4 acc[8];
    #pragma unroll
    for (int r = 0; r < 8; ++r)
        acc[r] = make_float4(bs[c], bs[c + 1], bs[c + 2], bs[c + 3]);

    if (in_f32) {
        const float* in = (const float*)inv;
        for (int k = 0; k < D; k += 4) {
            float4 w0 = *(const float4*)&Ws[(k + 0) * D + c];
            float4 w1 = *(const float4*)&Ws[(k + 1) * D + c];
            float4 w2 = *(const float4*)&Ws[(k + 2) * D + c];
            float4 w3 = *(const float4*)&Ws[(k + 3) * D + c];
            #pragma unroll
            for (int r = 0; r < 8; ++r) {
                float4 a = *(const float4*)(in + rIdx[r] * D + k);
                acc[r].x += a.x * w0.x + a.y * w1.x + a.z * w2.x + a.w * w3.x;
                acc[r].y += a.x * w0.y + a.y * w1.y + a.z * w2.y + a.w * w3.y;
                acc[r].z += a.x * w0.z + a.y * w1.z + a.z * w2.z + a.w * w3.z;
                acc[r].w += a.x * w0.w + a.y * w1.w + a.z * w2.w + a.w * w3.w;
            }
        }
    } else {
        const unsigned short* in = (const unsigned short*)inv;
        for (int k = 0; k < D; k += 4) {
            float4 w0 = *(const float4*)&Ws[(k + 0) * D + c];
            float4 w1 = *(const float4*)&Ws[(k + 1) * D + c];
            float4 w2 = *(const float4*)&Ws[(k + 2) * D + c];
            float4 w3 = *(const float4*)&Ws[(k + 3) * D + c];
            #pragma unroll
            for (int r = 0; r < 8; ++r) {
                ushort4 u = *(const ushort4*)(in + rIdx[r] * D + k);
                float ax = bf2f(u.x), ay = bf2f(u.y), az = bf2f(u.z), aw = bf2f(u.w);
                acc[r].x += ax * w0.x + ay * w1.x + az * w2.x + aw * w3.x;
                acc[r].y += ax * w0.y + ay * w1.y + az * w2.y + aw * w3.y;
                acc[r].z += ax * w0.z + ay * w1.z + az * w2.z + aw * w3.z;
                acc[r].w += ax * w0.w + ay * w1.w + az * w2.w + aw * w3.w;
            }
        }
    }

    #pragma unroll
    for (int r = 0; r < 8; ++r) {
        int row = row0 + r;
        if (row >= nNodes) break;
        if (out_f32) {
            ((float4*)outv)[(size_t)row * 32 + cg] = acc[r];
        } else {
            ushort4 o;
            o.x = f2bf(acc[r].x); o.y = f2bf(acc[r].y);
            o.z = f2bf(acc[r].z); o.w = f2bf(acc[r].w);
            ((ushort4*)outv)[(size_t)row * 32 + cg] = o;
        }
    }
}

// ---------- pass A: two-scan LDS binning of edges into per-group runs ----------
// scan1: count this block's edges per group (LDS). reserve: ONE global atomicAdd
// per (block,group). scan2: scatter packed (s | r<<20) into the reserved dense run.
// Global atomics: ~blocks*NB << E. Writes: contiguous runs -> line reuse.
__global__ __launch_bounds__(256) void bin_edges(
    const void* __restrict__ eiv, int* __restrict__ gcnt, unsigned int* __restrict__ grp,
    int* __restrict__ ovfCnt, int* __restrict__ ovfHead, int2* __restrict__ ovf,
    int nEdges, int NB, int CAPB, int nPer, const int* __restrict__ flags)
{
    __shared__ int cnts[NBMAX];
    __shared__ int run[NBMAX];

    const int e0 = blockIdx.x * nPer;
    int e1 = e0 + nPer; if (e1 > nEdges) e1 = nEdges;
    const int i64 = flags[1];
    const long long* ei64 = (const long long*)eiv;
    const int* ei32 = (const int*)eiv;

    for (int i = threadIdx.x; i < NB; i += 256) cnts[i] = 0;
    __syncthreads();

    for (int e = e0 + threadIdx.x; e < e1; e += 256) {
        int d = i64 ? (int)ei64[(size_t)nEdges + e] : ei32[(size_t)nEdges + e];
        atomicAdd(&cnts[d >> 6], 1);
    }
    __syncthreads();

    for (int g = threadIdx.x; g < NB; g += 256) {
        int c = cnts[g];
        run[g] = (c > 0) ? atomicAdd(&gcnt[(size_t)g * 16], c) : 0;
    }
    __syncthreads();

    for (int e = e0 + threadIdx.x; e < e1; e += 256) {
        int s, d;
        if (i64) { s = (int)ei64[e]; d = (int)ei64[(size_t)nEdges + e]; }
        else     { s = ei32[e];      d = ei32[(size_t)nEdges + e]; }
        int g = d >> 6;
        int pos = atomicAdd(&run[g], 1);
        unsigned int p = (unsigned int)s | ((unsigned int)(d & 63) << 20);
        if (pos < CAPB) {
            grp[(size_t)g * CAPB + pos] = p;
        } else {
            int idx = atomicAdd(ovfCnt, 1);   // < nEdges guaranteed
            int old = atomicExch(&ovfHead[g], idx);
            ovf[idx] = make_int2(old, (int)p);
        }
    }
}

// ---------- pass B: per-group counting-sort by row (LDS), then REGISTER accumulate ----------
// Each wave owns rows r = w, w+4, ...: exclusive ownership -> no atomics on data.
// y-row loads 4-deep independent per wave (proven gather pattern).
__global__ __launch_bounds__(256, 4) void sort_accum(
    const unsigned int* __restrict__ yu,   // y as bf16 pairs (N x 64 uints)
    const int* __restrict__ gcnt, const unsigned int* __restrict__ grp,
    const int* __restrict__ ovfHead, const int2* __restrict__ ovf,
    const void* __restrict__ bv, void* __restrict__ outv,
    int nNodes, int CAPB, const int* __restrict__ flags)
{
    __shared__ unsigned int sorted[CAPB_MAX];   // 8 KB: src indices, row-sorted
    __shared__ int rcnt[GRP], roff[GRP], rrun[GRP];

    const int g = blockIdx.x;
    const int n0 = g << 6;
    const int tid = threadIdx.x;
    const int w = tid >> 6, lane = tid & 63;
    const int xf32 = flags[0];

    if (tid < GRP) rcnt[tid] = 0;
    __syncthreads();

    const int cnt = gcnt[(size_t)g * 16];
    const int m = cnt < CAPB ? cnt : CAPB;

    for (int i = tid; i < m; i += 256)
        atomicAdd(&rcnt[grp[(size_t)g * CAPB + i] >> 20], 1);
    __syncthreads();

    if (w == 0) {   // exclusive prefix over 64 bins (wave 0)
        int v = rcnt[lane];
        int sc = v;
        #pragma unroll
        for (int o = 1; o < 64; o <<= 1) {
            int t = __shfl_up(sc, o);
            if (lane >= o) sc += t;
        }
        roff[lane] = sc - v;
        rrun[lane] = sc - v;
    }
    __syncthreads();

    for (int i = tid; i < m; i += 256) {
        unsigned int p = grp[(size_t)g * CAPB + i];
        int pos = atomicAdd(&rrun[p >> 20], 1);
        sorted[pos] = p & 0xFFFFFu;
    }
    __syncthreads();

    const bool hasOvf = (cnt > CAPB);   // statistically never

    for (int r = w; r < GRP; r += 4) {
        int node = n0 + r;
        if (node >= nNodes) break;
        const int j0 = roff[r], dg = rcnt[r];

        float a0 = 0.f, a1 = 0.f, a2 = 0.f, a3 = 0.f;
        float b0 = 0.f, b1 = 0.f, b2 = 0.f, b3 = 0.f;
        int j = 0;
        for (; j + 4 <= dg; j += 4) {
            unsigned int s0 = sorted[j0 + j + 0];
            unsigned int s1 = sorted[j0 + j + 1];
            unsigned int s2 = sorted[j0 + j + 2];
            unsigned int s3 = sorted[j0 + j + 3];
            unsigned int u0 = yu[(size_t)s0 * 64 + lane];
            unsigned int u1 = yu[(size_t)s1 * 64 + lane];
            unsigned int u2 = yu[(size_t)s2 * 64 + lane];
            unsigned int u3 = yu[(size_t)s3 * 64 + lane];
            a0 += bits2f(u0 << 16); b0 += bits2f(u0 & 0xFFFF0000u);
            a1 += bits2f(u1 << 16); b1 += bits2f(u1 & 0xFFFF0000u);
            a2 += bits2f(u2 << 16); b2 += bits2f(u2 & 0xFFFF0000u);
            a3 += bits2f(u3 << 16); b3 += bits2f(u3 & 0xFFFF0000u);
        }
        for (; j < dg; ++j) {
            unsigned int s0 = sorted[j0 + j];
            unsigned int u0 = yu[(size_t)s0 * 64 + lane];
            a0 += bits2f(u0 << 16); b0 += bits2f(u0 & 0xFFFF0000u);
        }

        if (hasOvf) {   // pathological fallback: filter-walk chain for this row
            int cur = ovfHead[g];
            while (cur >= 0) {
                int2 t = ovf[cur];
                unsigned int p = (unsigned int)t.y;
                if ((int)(p >> 20) == r) {
                    unsigned int u = yu[(size_t)(p & 0xFFFFFu) * 64 + lane];
                    a0 += bits2f(u << 16); b0 += bits2f(u & 0xFFFF0000u);
                }
                cur = t.x;
            }
        }

        float f0 = (a0 + a1) + (a2 + a3);
        float f1 = (b0 + b1) + (b2 + b3);

        if (xf32) {
            float2 bb = ((const float2*)bv)[lane];
            float2 o; o.x = f0 + bb.x; o.y = f1 + bb.y;
            ((float2*)outv)[(size_t)node * 64 + lane] = o;
        } else {
            unsigned int ub = ((const unsigned int*)bv)[lane];
            f0 += bits2f(ub << 16);
            f1 += bits2f(ub & 0xFFFF0000u);
            unsigned int o = ((unsigned int)f2bf(f0)) | (((unsigned int)f2bf(f1)) << 16);
            ((unsigned int*)outv)[(size_t)node * 64 + lane] = o;
        }
    }
}

// ---------- fallback scatter (atomics) if ws too small / N too large ----------
__global__ __launch_bounds__(256) void scatter_kernel(
    const void* __restrict__ xv, const void* __restrict__ eiv,
    float* __restrict__ agg, int nEdges, const int* __restrict__ flags)
{
    long long tid = (long long)blockIdx.x * 256 + threadIdx.x;
    int e = (int)(tid >> 5);
    if (e >= nEdges) return;
    int q = (int)tid & 31;

    const int xf32 = flags[0];
    int s, d;
    if (flags[1]) {
        const long long* ei = (const long long*)eiv;
        s = (int)ei[e]; d = (int)ei[(size_t)nEdges + e];
    } else {
        const int* ei = (const int*)eiv;
        s = ei[e]; d = ei[(size_t)nEdges + e];
    }
    float4 v;
    if (xf32) {
        v = ((const float4*)xv)[(size_t)s * 32 + q];
    } else {
        ushort4 u = ((const ushort4*)xv)[(size_t)s * 32 + q];
        v.x = bf2f(u.x); v.y = bf2f(u.y); v.z = bf2f(u.z); v.w = bf2f(u.w);
    }
    float* ap = agg + (size_t)d * D + q * 4;
    atomicAdd(ap + 0, v.x);
    atomicAdd(ap + 1, v.y);
    atomicAdd(ap + 2, v.z);
    atomicAdd(ap + 3, v.w);
}

static inline size_t alignup(size_t v, size_t a) { return (v + a - 1) & ~(a - 1); }

extern "C" void kernel_launch(void* const* d_in, const int* in_sizes, int n_in,
                              void* d_out, int out_size, void* d_ws, size_t ws_size,
                              hipStream_t stream) {
    const void* x  = d_in[0];
    const void* ei = d_in[1];
    const void* W  = d_in[2];
    const void* b  = d_in[3];

    const int nNodes = in_sizes[0] / D;
    const int nEdges = in_sizes[1] / 2;
    const int NB = (nNodes + GRP - 1) / GRP;

    int* flags = (int*)d_ws;
    probe_kernel<<<1, 64, 0, stream>>>((const unsigned short*)x, (const long long*)ei,
                                       nNodes, flags);

    // fast path ws layout:
    // flags(512) | gcnt[NB*16] | ovfCnt(256B) | ovfHead[NB] | ovf[E] int2 | grp[NB*CAPB] | y[N*D] bf16
    int CAPB = 0;
    size_t off_gcnt = 512, off_ovfc = 0, off_head = 0, off_ovf = 0, off_grp = 0, off_y = 0;
    if (nNodes < (1 << 20) && NB <= NBMAX) {   // packed format + LDS bin limits
        int cap = CAPB_MAX;
        size_t ogcnt = 512;
        size_t oovfc = alignup(ogcnt + 64ull * NB, 256);
        size_t ohead = oovfc + 256;
        size_t oovf  = alignup(ohead + 4ull * NB, 256);
        size_t ogrp  = alignup(oovf + 8ull * nEdges, 256);
        size_t oy    = alignup(ogrp + 4ull * cap * NB, 512);
        size_t need  = oy + (size_t)nNodes * D * 2;   // y bf16
        if (ws_size >= need) {
            CAPB = cap; off_gcnt = ogcnt; off_ovfc = oovfc; off_head = ohead;
            off_ovf = oovf; off_grp = ogrp; off_y = oy;
        }
    }

    const int mblocks = (nNodes + 63) / 64;

    if (CAPB > 0) {
        int*          gcnt    = (int*)((char*)d_ws + off_gcnt);
        int*          ovfCnt  = (int*)((char*)d_ws + off_ovfc);
        int*          ovfHead = (int*)((char*)d_ws + off_head);
        int2*         ovf     = (int2*)((char*)d_ws + off_ovf);
        unsigned int* grp     = (unsigned int*)((char*)d_ws + off_grp);
        void*         y       = (void*)((char*)d_ws + off_y);

        // y = x @ W   (no bias; y stored bf16)
        gemm_kernel<<<mblocks, 256, 0, stream>>>(x, W, b, y, nNodes, flags,
                                                 /*in_f32*/-1, /*out_f32*/0, /*bias*/0);

        hipMemsetAsync(gcnt, 0, off_head - off_gcnt, stream);   // gcnt = 0, ovfCnt = 0
        hipMemsetAsync(ovfHead, 0xFF, 4ull * NB, stream);       // heads = -1

        const int ABLK = 256;
        const int nPer = (nEdges + ABLK - 1) / ABLK;
        bin_edges<<<ABLK, 256, 0, stream>>>(ei, gcnt, grp, ovfCnt, ovfHead, ovf,
                                            nEdges, NB, CAPB, nPer, flags);

        sort_accum<<<NB, 256, 0, stream>>>((const unsigned int*)y, gcnt, grp,
                                           ovfHead, ovf, b, d_out,
                                           nNodes, CAPB, flags);
    } else {
        // fallback: atomic scatter into fp32 agg, then out = agg @ W + b
        float* agg = (float*)((char*)d_ws + 512);
        hipMemsetAsync(agg, 0, (size_t)nNodes * D * sizeof(float), stream);
        long long total = (long long)nEdges * 32;
        int sblocks = (int)((total + 255) / 256);
        scatter_kernel<<<sblocks, 256, 0, stream>>>(x, ei, agg, nEdges, flags);
        gemm_kernel<<<mblocks, 256, 0, stream>>>(agg, W, b, d_out, nNodes, flags,
                                                 /*in_f32*/1, /*out_f32*/-1, /*bias*/1);
    }
}